// Round 5
// baseline (125.476 us; speedup 1.0000x reference)
//
#include <hip/hip_runtime.h>

// ---------------------------------------------------------------------------
// SpeciesSpecificNetworkBranch — dense bf16 MFMA version (no gather/scatter).
//
// Rows in natural order (pure streaming); each 32-row tile computes ALL 5
// species' chains (5x MFMA redundancy is cheap) and per-lane selects by
// species id. Weights/biases BN-folded + frag-packed by k_pre, staged to LDS.
//
// R4 -> R5: block 256 -> 512 threads. LDS 43KB still allows 3 blocks/CU, so
// waves/CU goes 12 -> 24 (6/SIMD, VGPR 72 <= 85 cap) — doubled latency hiding
// for the per-tile MFMA dependency chains. Also: 0.92 branch-weight folded
// into Wshf/bshf (relu(z)*c == relu(c*z), c>0), per-species __any skip.
//
// math: z1 = W1^T x + b1
//       z2 = W2f^T relu(z1) + Wsc^T x + bias2f     (W2f = diag(A1) W2)
//       out = relu(Wshf_s^T relu(z2) + bshf_s)     (0.92 pre-folded)
// C'[feature][sample] from mfma_f32_32x32x16_bf16; sample lane-local, so
// relu + v_cvt_pk_bf16_f32 + permlane32_swap chains layers in registers.
// ---------------------------------------------------------------------------

#define EPSBN 1e-5f
#define TPB 512
#define NBLK 768   // 3 blocks/CU on 256 CUs

typedef __attribute__((ext_vector_type(8))) short bf16x8;
typedef __attribute__((ext_vector_type(16))) float f32x16;
typedef __attribute__((ext_vector_type(4))) unsigned u32x4;

union FU { unsigned u[4]; bf16x8 v; u32x4 q; };

static __device__ __forceinline__ unsigned pkbf(float lo, float hi) {
    unsigned r;
    asm("v_cvt_pk_bf16_f32 %0, %1, %2" : "=v"(r) : "v"(lo), "v"(hi));
    return r;
}

// --- pre-pack: fold BN (and 0.92) into weights/biases, pack MFMA A-frags ---
// wfrag uints [s][m][c][64][4]  (m: 0=W1 1=Wsc 2=W2f 3=Wshf), 10240 words
// bconst floats [s][q][hi][16]  (q: 0=b1 1=bias2f 2=bshf), 480 floats
__global__ void k_pre(unsigned* __restrict__ wfrag, float* __restrict__ bconst,
                      const float* __restrict__ W1, const float* __restrict__ b1,
                      const float* __restrict__ g1, const float* __restrict__ be1,
                      const float* __restrict__ mu1, const float* __restrict__ va1,
                      const float* __restrict__ W2, const float* __restrict__ b2,
                      const float* __restrict__ g2, const float* __restrict__ be2,
                      const float* __restrict__ mu2, const float* __restrict__ va2,
                      const float* __restrict__ Wsc, const float* __restrict__ bsc,
                      const float* __restrict__ Wsh, const float* __restrict__ bsh) {
    if (blockIdx.x < 40) {
        const int i = blockIdx.x * 256 + threadIdx.x;   // wfrag word index
        const int p = i & 3, l = (i >> 2) & 63, c = (i >> 8) & 1;
        const int m = (i >> 9) & 3, s = i >> 11;
        const int ln = l & 31, hi = l >> 5;
        const int k0 = c * 16 + hi * 8 + 2 * p;
        float lo, hv;
        if (m == 0)      { lo = W1[s*1024 + k0*32 + ln];  hv = W1[s*1024 + (k0+1)*32 + ln]; }
        else if (m == 1) { lo = Wsc[s*1024 + k0*32 + ln]; hv = Wsc[s*1024 + (k0+1)*32 + ln]; }
        else if (m == 2) {
            float A0 = g1[s*32+k0]   * rsqrtf(va1[s*32+k0]   + EPSBN);
            float A1 = g1[s*32+k0+1] * rsqrtf(va1[s*32+k0+1] + EPSBN);
            lo = A0 * W2[s*1024 + k0*32 + ln]; hv = A1 * W2[s*1024 + (k0+1)*32 + ln];
        } else {
            float A0 = 0.92f * g2[s*32+k0]   * rsqrtf(va2[s*32+k0]   + EPSBN);
            float A1 = 0.92f * g2[s*32+k0+1] * rsqrtf(va2[s*32+k0+1] + EPSBN);
            lo = A0 * Wsh[k0*32 + ln]; hv = A1 * Wsh[(k0+1)*32 + ln];
        }
        wfrag[i] = pkbf(lo, hv);
    } else {
        for (int i = threadIdx.x; i < 480; i += 256) {
            const int reg = i & 15, hi = (i >> 4) & 1, t = i >> 5;
            const int q = t % 3, s = t / 3;
            const int r = (reg & 3) + 8 * (reg >> 2) + 4 * hi;
            float v;
            if (q == 0) v = b1[s*32 + r];
            else if (q == 1) {
                v = b2[s*32 + r] + bsc[s*32 + r];
                for (int k = 0; k < 32; ++k) {
                    float A = g1[s*32+k] * rsqrtf(va1[s*32+k] + EPSBN);
                    float C = be1[s*32+k] - mu1[s*32+k] * A;
                    v = fmaf(C, W2[s*1024 + k*32 + r], v);
                }
            } else {
                v = bsh[r];
                for (int k = 0; k < 32; ++k) {
                    float A = g2[s*32+k] * rsqrtf(va2[s*32+k] + EPSBN);
                    float C = be2[s*32+k] - mu2[s*32+k] * A;
                    v = fmaf(C, Wsh[k*32 + r], v);
                }
                v *= 0.92f;
            }
            bconst[i] = v;
        }
    }
}

// relu-only transition: C' acc -> next layer's B-frags (cvt_pk + permlane32).
static __device__ __forceinline__ void reluT(const f32x16& c, bf16x8& f0, bf16x8& f1) {
    unsigned p[8];
    #pragma unroll
    for (int i = 0; i < 8; ++i)
        p[i] = pkbf(fmaxf(c[2 * i], 0.f), fmaxf(c[2 * i + 1], 0.f));
    auto s0 = __builtin_amdgcn_permlane32_swap(p[0], p[2], false, false);
    auto s1 = __builtin_amdgcn_permlane32_swap(p[1], p[3], false, false);
    auto s2 = __builtin_amdgcn_permlane32_swap(p[4], p[6], false, false);
    auto s3 = __builtin_amdgcn_permlane32_swap(p[5], p[7], false, false);
    FU u0, u1;
    u0.u[0] = s0[0]; u0.u[1] = s1[0]; u0.u[2] = s0[1]; u0.u[3] = s1[1];
    u1.u[0] = s2[0]; u1.u[1] = s3[0]; u1.u[2] = s2[1]; u1.u[3] = s3[1];
    f0 = u0.v; f1 = u1.v;
}

struct XR { float4 a, b, c, d; };

static __device__ __forceinline__ XR ldx(const float* __restrict__ X, long ofs, int hi) {
    const float* xb = X + ofs + hi * 8;
    XR r;
    r.a = *(const float4*)(xb);
    r.b = *(const float4*)(xb + 4);
    r.c = *(const float4*)(xb + 16);
    r.d = *(const float4*)(xb + 20);
    return r;
}

static __device__ __forceinline__ void cvtx(const XR& x, bf16x8& b0, bf16x8& b1) {
    FU u0, u1;
    u0.u[0] = pkbf(x.a.x, x.a.y); u0.u[1] = pkbf(x.a.z, x.a.w);
    u0.u[2] = pkbf(x.b.x, x.b.y); u0.u[3] = pkbf(x.b.z, x.b.w);
    u1.u[0] = pkbf(x.c.x, x.c.y); u1.u[1] = pkbf(x.c.z, x.c.w);
    u1.u[2] = pkbf(x.d.x, x.d.y); u1.u[3] = pkbf(x.d.z, x.d.w);
    b0 = u0.v; b1 = u1.v;
}

__global__ __launch_bounds__(TPB, 6) void k_main(
    const float* __restrict__ X, const int* __restrict__ sid,
    const unsigned* __restrict__ wfrag, const float* __restrict__ bconst,
    float* __restrict__ out, int B, int ntiles) {
    __shared__ unsigned wlds[10240];
    __shared__ float clds[480];
    for (int i = threadIdx.x; i < 10240; i += TPB) wlds[i] = wfrag[i];
    for (int i = threadIdx.x; i < 480; i += TPB) clds[i] = bconst[i];
    __syncthreads();

    const int l  = threadIdx.x & 63;
    const int ln = l & 31;
    const int hi = l >> 5;
    const int wid = (blockIdx.x * TPB + threadIdx.x) >> 6;
    const int nw  = (gridDim.x * TPB) >> 6;

    int t = wid;
    if (t >= ntiles) return;

    // prefetch first tile
    int rc = min(t * 32 + ln, B - 1);
    XR xc = ldx(X, (long)rc * 32, hi);
    int sv = sid[rc];

    for (; t < ntiles; t += nw) {
        bf16x8 bx0, bx1;
        cvtx(xc, bx0, bx1);
        const int svc  = sv;
        const int rowc = t * 32 + ln;

        // prefetch next grid-stride tile
        const int tn = t + nw;
        if (tn < ntiles) {
            int r2 = min(tn * 32 + ln, B - 1);
            xc = ldx(X, (long)r2 * 32, hi);
            sv = sid[r2];
        }

        // opaque LDS bases: defeat LICM (else 160 loop-invariant ds_reads get
        // hoisted into registers and spill)
        int zero = 0;
        asm volatile("" : "+v"(zero));
        const unsigned* wl = wlds + zero;
        const float*    cl = clds + zero;

        float acc[16];
        #pragma unroll
        for (int r = 0; r < 16; ++r) acc[r] = 0.f;

        #pragma unroll
        for (int s = 0; s < 5; ++s) {
            if (__any(svc == s)) {
                f32x16 a1 = *(const f32x16*)(cl + ((s * 3 + 0) * 2 + hi) * 16);
                f32x16 a2 = *(const f32x16*)(cl + ((s * 3 + 1) * 2 + hi) * 16);
                FU w00, w01, w10, w11, w20, w21, w30, w31;
                w00.q = *(const u32x4*)(wl + (((s * 4 + 0) * 2 + 0) * 64 + l) * 4);
                w01.q = *(const u32x4*)(wl + (((s * 4 + 0) * 2 + 1) * 64 + l) * 4);
                a1 = __builtin_amdgcn_mfma_f32_32x32x16_bf16(w00.v, bx0, a1, 0, 0, 0);
                a1 = __builtin_amdgcn_mfma_f32_32x32x16_bf16(w01.v, bx1, a1, 0, 0, 0);
                w10.q = *(const u32x4*)(wl + (((s * 4 + 1) * 2 + 0) * 64 + l) * 4);
                w11.q = *(const u32x4*)(wl + (((s * 4 + 1) * 2 + 1) * 64 + l) * 4);
                a2 = __builtin_amdgcn_mfma_f32_32x32x16_bf16(w10.v, bx0, a2, 0, 0, 0);
                a2 = __builtin_amdgcn_mfma_f32_32x32x16_bf16(w11.v, bx1, a2, 0, 0, 0);
                bf16x8 h0, h1;
                reluT(a1, h0, h1);
                w20.q = *(const u32x4*)(wl + (((s * 4 + 2) * 2 + 0) * 64 + l) * 4);
                w21.q = *(const u32x4*)(wl + (((s * 4 + 2) * 2 + 1) * 64 + l) * 4);
                a2 = __builtin_amdgcn_mfma_f32_32x32x16_bf16(w20.v, h0, a2, 0, 0, 0);
                a2 = __builtin_amdgcn_mfma_f32_32x32x16_bf16(w21.v, h1, a2, 0, 0, 0);
                bf16x8 g0, g1;
                reluT(a2, g0, g1);
                f32x16 a3 = *(const f32x16*)(cl + ((s * 3 + 2) * 2 + hi) * 16);
                w30.q = *(const u32x4*)(wl + (((s * 4 + 3) * 2 + 0) * 64 + l) * 4);
                w31.q = *(const u32x4*)(wl + (((s * 4 + 3) * 2 + 1) * 64 + l) * 4);
                a3 = __builtin_amdgcn_mfma_f32_32x32x16_bf16(w30.v, g0, a3, 0, 0, 0);
                a3 = __builtin_amdgcn_mfma_f32_32x32x16_bf16(w31.v, g1, a3, 0, 0, 0);

                const bool m = (svc == s);
                #pragma unroll
                for (int r = 0; r < 16; ++r) acc[r] = m ? a3[r] : acc[r];
            }
        }

        if (rowc < B) {
            float* op = out + (long)rowc * 32 + hi * 4;
            #pragma unroll
            for (int q = 0; q < 4; ++q) {
                float4 v;
                v.x = fmaxf(acc[4 * q + 0], 0.f);
                v.y = fmaxf(acc[4 * q + 1], 0.f);
                v.z = fmaxf(acc[4 * q + 2], 0.f);
                v.w = fmaxf(acc[4 * q + 3], 0.f);
                *(float4*)(op + q * 8) = v;
            }
        }
    }
}

extern "C" void kernel_launch(void* const* d_in, const int* in_sizes, int n_in,
                              void* d_out, int out_size, void* d_ws, size_t ws_size,
                              hipStream_t stream) {
    const float* X   = (const float*)d_in[0];
    const int*   sid = (const int*)d_in[1];
    const float* W1  = (const float*)d_in[2];
    const float* b1  = (const float*)d_in[3];
    const float* g1  = (const float*)d_in[4];
    const float* be1 = (const float*)d_in[5];
    const float* mu1 = (const float*)d_in[6];
    const float* va1 = (const float*)d_in[7];
    const float* W2  = (const float*)d_in[8];
    const float* b2  = (const float*)d_in[9];
    const float* g2  = (const float*)d_in[10];
    const float* be2 = (const float*)d_in[11];
    const float* mu2 = (const float*)d_in[12];
    const float* va2 = (const float*)d_in[13];
    const float* Wsc = (const float*)d_in[14];
    const float* bsc = (const float*)d_in[15];
    const float* Wsh = (const float*)d_in[16];
    const float* bsh = (const float*)d_in[17];
    float* out = (float*)d_out;
    const int B = in_sizes[1];

    unsigned* wfrag = (unsigned*)d_ws;          // 10240 u32
    float* bconst   = (float*)(wfrag + 10240);  // 480 f32

    k_pre<<<41, 256, 0, stream>>>(wfrag, bconst,
                                  W1, b1, g1, be1, mu1, va1,
                                  W2, b2, g2, be2, mu2, va2,
                                  Wsc, bsc, Wsh, bsh);

    const int ntiles = (B + 31) / 32;
    const int wpb = TPB / 64;
    const int nblocks = min(NBLK, (ntiles + wpb - 1) / wpb);
    k_main<<<nblocks, TPB, 0, stream>>>(X, sid, wfrag, bconst, out, B, ntiles);
}

// Round 6
// 108.684 us; speedup vs baseline: 1.1545x; 1.1545x over previous
//
#include <hip/hip_runtime.h>

// ---------------------------------------------------------------------------
// SpeciesSpecificNetworkBranch — dense bf16 MFMA, no-LDS, dual-tile version.
//
// Rows in natural order (pure streaming). Each wave-iteration processes TWO
// 32-row tiles (independent MFMA chains -> 2x ILP, weight reads amortized
// over 64 rows). All 5 species' chains computed; each row is stored exactly
// once via exec-masked stores in its species' iteration (pieces of a row are
// issued together -> L2 write-combines to full sectors).
//
// Weights/biases BN-folded (+0.92) and frag-packed by k_pre; k_main reads
// them from global (L1/L2-hot 42KB table). Opaque pointer defeats LICM so
// the table is NOT hoisted into registers (would spill).
//
// R5 lesson: __launch_bounds__(512,6) caused a 40-VGPR cap + ~160MB scratch
// spill traffic. 256-thread blocks, (256,3) cap 170, zero spill.
//
// math: z1 = W1^T x + b1
//       z2 = W2f^T relu(z1) + Wsc^T x + bias2f     (W2f = diag(A1) W2)
//       out = relu(Wshf_s^T relu(z2) + bshf_s)     (0.92 pre-folded)
// C'[feature][sample] via mfma_f32_32x32x16_bf16; sample lane-local, so
// relu + v_cvt_pk_bf16_f32 + permlane32_swap chains layers in registers.
// ---------------------------------------------------------------------------

#define EPSBN 1e-5f
#define TPB 256
#define MAXBLK 2048

typedef __attribute__((ext_vector_type(8))) short bf16x8;
typedef __attribute__((ext_vector_type(16))) float f32x16;
typedef __attribute__((ext_vector_type(4))) unsigned u32x4;

union FU { unsigned u[4]; bf16x8 v; u32x4 q; };

static __device__ __forceinline__ unsigned pkbf(float lo, float hi) {
    unsigned r;
    asm("v_cvt_pk_bf16_f32 %0, %1, %2" : "=v"(r) : "v"(lo), "v"(hi));
    return r;
}

// --- pre-pack: fold BN (and 0.92) into weights/biases, pack MFMA A-frags ---
// wfrag uints [s][m][c][64][4]  (m: 0=W1 1=Wsc 2=W2f 3=Wshf), 10240 words
// bconst floats [s][q][hi][16]  (q: 0=b1 1=bias2f 2=bshf), 480 floats
__global__ void k_pre(unsigned* __restrict__ wfrag, float* __restrict__ bconst,
                      const float* __restrict__ W1, const float* __restrict__ b1,
                      const float* __restrict__ g1, const float* __restrict__ be1,
                      const float* __restrict__ mu1, const float* __restrict__ va1,
                      const float* __restrict__ W2, const float* __restrict__ b2,
                      const float* __restrict__ g2, const float* __restrict__ be2,
                      const float* __restrict__ mu2, const float* __restrict__ va2,
                      const float* __restrict__ Wsc, const float* __restrict__ bsc,
                      const float* __restrict__ Wsh, const float* __restrict__ bsh) {
    if (blockIdx.x < 40) {
        const int i = blockIdx.x * 256 + threadIdx.x;   // wfrag word index
        const int p = i & 3, l = (i >> 2) & 63, c = (i >> 8) & 1;
        const int m = (i >> 9) & 3, s = i >> 11;
        const int ln = l & 31, hi = l >> 5;
        const int k0 = c * 16 + hi * 8 + 2 * p;
        float lo, hv;
        if (m == 0)      { lo = W1[s*1024 + k0*32 + ln];  hv = W1[s*1024 + (k0+1)*32 + ln]; }
        else if (m == 1) { lo = Wsc[s*1024 + k0*32 + ln]; hv = Wsc[s*1024 + (k0+1)*32 + ln]; }
        else if (m == 2) {
            float A0 = g1[s*32+k0]   * rsqrtf(va1[s*32+k0]   + EPSBN);
            float A1 = g1[s*32+k0+1] * rsqrtf(va1[s*32+k0+1] + EPSBN);
            lo = A0 * W2[s*1024 + k0*32 + ln]; hv = A1 * W2[s*1024 + (k0+1)*32 + ln];
        } else {
            float A0 = 0.92f * g2[s*32+k0]   * rsqrtf(va2[s*32+k0]   + EPSBN);
            float A1 = 0.92f * g2[s*32+k0+1] * rsqrtf(va2[s*32+k0+1] + EPSBN);
            lo = A0 * Wsh[k0*32 + ln]; hv = A1 * Wsh[(k0+1)*32 + ln];
        }
        wfrag[i] = pkbf(lo, hv);
    } else {
        for (int i = threadIdx.x; i < 480; i += 256) {
            const int reg = i & 15, hi = (i >> 4) & 1, t = i >> 5;
            const int q = t % 3, s = t / 3;
            const int r = (reg & 3) + 8 * (reg >> 2) + 4 * hi;
            float v;
            if (q == 0) v = b1[s*32 + r];
            else if (q == 1) {
                v = b2[s*32 + r] + bsc[s*32 + r];
                for (int k = 0; k < 32; ++k) {
                    float A = g1[s*32+k] * rsqrtf(va1[s*32+k] + EPSBN);
                    float C = be1[s*32+k] - mu1[s*32+k] * A;
                    v = fmaf(C, W2[s*1024 + k*32 + r], v);
                }
            } else {
                v = bsh[r];
                for (int k = 0; k < 32; ++k) {
                    float A = g2[s*32+k] * rsqrtf(va2[s*32+k] + EPSBN);
                    float C = be2[s*32+k] - mu2[s*32+k] * A;
                    v = fmaf(C, Wsh[k*32 + r], v);
                }
                v *= 0.92f;
            }
            bconst[i] = v;
        }
    }
}

// relu-only transition: C' acc -> next layer's B-frags (cvt_pk + permlane32).
static __device__ __forceinline__ void reluT(const f32x16& c, bf16x8& f0, bf16x8& f1) {
    unsigned p[8];
    #pragma unroll
    for (int i = 0; i < 8; ++i)
        p[i] = pkbf(fmaxf(c[2 * i], 0.f), fmaxf(c[2 * i + 1], 0.f));
    auto s0 = __builtin_amdgcn_permlane32_swap(p[0], p[2], false, false);
    auto s1 = __builtin_amdgcn_permlane32_swap(p[1], p[3], false, false);
    auto s2 = __builtin_amdgcn_permlane32_swap(p[4], p[6], false, false);
    auto s3 = __builtin_amdgcn_permlane32_swap(p[5], p[7], false, false);
    FU u0, u1;
    u0.u[0] = s0[0]; u0.u[1] = s1[0]; u0.u[2] = s0[1]; u0.u[3] = s1[1];
    u1.u[0] = s2[0]; u1.u[1] = s3[0]; u1.u[2] = s2[1]; u1.u[3] = s3[1];
    f0 = u0.v; f1 = u1.v;
}

struct XR { float4 a, b, c, d; };

static __device__ __forceinline__ XR ldx(const float* __restrict__ X, long ofs, int hi) {
    const float* xb = X + ofs + hi * 8;
    XR r;
    r.a = *(const float4*)(xb);
    r.b = *(const float4*)(xb + 4);
    r.c = *(const float4*)(xb + 16);
    r.d = *(const float4*)(xb + 20);
    return r;
}

static __device__ __forceinline__ void cvtx(const XR& x, bf16x8& b0, bf16x8& b1) {
    FU u0, u1;
    u0.u[0] = pkbf(x.a.x, x.a.y); u0.u[1] = pkbf(x.a.z, x.a.w);
    u0.u[2] = pkbf(x.b.x, x.b.y); u0.u[3] = pkbf(x.b.z, x.b.w);
    u1.u[0] = pkbf(x.c.x, x.c.y); u1.u[1] = pkbf(x.c.z, x.c.w);
    u1.u[2] = pkbf(x.d.x, x.d.y); u1.u[3] = pkbf(x.d.z, x.d.w);
    b0 = u0.v; b1 = u1.v;
}

static __device__ __forceinline__ void store_row(float* __restrict__ op, const f32x16& a3) {
    #pragma unroll
    for (int q = 0; q < 4; ++q) {
        float4 v;
        v.x = fmaxf(a3[4 * q + 0], 0.f);
        v.y = fmaxf(a3[4 * q + 1], 0.f);
        v.z = fmaxf(a3[4 * q + 2], 0.f);
        v.w = fmaxf(a3[4 * q + 3], 0.f);
        *(float4*)(op + q * 8) = v;
    }
}

__global__ __launch_bounds__(TPB, 3) void k_main(
    const float* __restrict__ X, const int* __restrict__ sid,
    const unsigned* __restrict__ wfrag, const float* __restrict__ bconst,
    float* __restrict__ out, int B, int npairs) {
    const int l  = threadIdx.x & 63;
    const int ln = l & 31;
    const int hi = l >> 5;
    const int wid = (blockIdx.x * TPB + threadIdx.x) >> 6;
    const int nw  = (gridDim.x * TPB) >> 6;

    int p = wid;
    if (p >= npairs) return;

    // prefetch first pair (2 tiles of 32 rows)
    int rA = min(p * 64 + ln, B - 1);
    int rB = min(p * 64 + 32 + ln, B - 1);
    XR xA = ldx(X, (long)rA * 32, hi);
    XR xB = ldx(X, (long)rB * 32, hi);
    int sA = sid[rA], sB = sid[rB];

    for (; p < npairs; p += nw) {
        bf16x8 bxA0, bxA1, bxB0, bxB1;
        cvtx(xA, bxA0, bxA1);
        cvtx(xB, bxB0, bxB1);
        const int svA = sA, svB = sB;
        const int rowA = p * 64 + ln;
        const int rowB = p * 64 + 32 + ln;

        // prefetch next pair
        const int pn = p + nw;
        if (pn < npairs) {
            rA = min(pn * 64 + ln, B - 1);
            rB = min(pn * 64 + 32 + ln, B - 1);
            xA = ldx(X, (long)rA * 32, hi);
            xB = ldx(X, (long)rB * 32, hi);
            sA = sid[rA]; sB = sid[rB];
        }

        // opaque bases: defeat LICM (else the 42KB table hoists into regs -> spill)
        int zero = 0;
        asm volatile("" : "+v"(zero));
        const unsigned* wl = wfrag + zero;
        const float*    cl = bconst + zero;

        #pragma unroll
        for (int s = 0; s < 5; ++s) {
            const unsigned* wp = wl + s * 2048;
            FU w00, w01, w10, w11, w20, w21, w30, w31;
            w00.q = *(const u32x4*)(wp + (0 * 64 + l) * 4);
            w01.q = *(const u32x4*)(wp + (1 * 64 + l) * 4);
            w10.q = *(const u32x4*)(wp + (2 * 64 + l) * 4);
            w11.q = *(const u32x4*)(wp + (3 * 64 + l) * 4);

            f32x16 a1A = *(const f32x16*)(cl + ((s * 3 + 0) * 2 + hi) * 16);
            f32x16 a2A = *(const f32x16*)(cl + ((s * 3 + 1) * 2 + hi) * 16);
            f32x16 a1B = a1A, a2B = a2A;

            a1A = __builtin_amdgcn_mfma_f32_32x32x16_bf16(w00.v, bxA0, a1A, 0, 0, 0);
            a1B = __builtin_amdgcn_mfma_f32_32x32x16_bf16(w00.v, bxB0, a1B, 0, 0, 0);
            a1A = __builtin_amdgcn_mfma_f32_32x32x16_bf16(w01.v, bxA1, a1A, 0, 0, 0);
            a1B = __builtin_amdgcn_mfma_f32_32x32x16_bf16(w01.v, bxB1, a1B, 0, 0, 0);
            a2A = __builtin_amdgcn_mfma_f32_32x32x16_bf16(w10.v, bxA0, a2A, 0, 0, 0);
            a2B = __builtin_amdgcn_mfma_f32_32x32x16_bf16(w10.v, bxB0, a2B, 0, 0, 0);
            a2A = __builtin_amdgcn_mfma_f32_32x32x16_bf16(w11.v, bxA1, a2A, 0, 0, 0);
            a2B = __builtin_amdgcn_mfma_f32_32x32x16_bf16(w11.v, bxB1, a2B, 0, 0, 0);

            bf16x8 hA0, hA1, hB0, hB1;
            reluT(a1A, hA0, hA1);
            reluT(a1B, hB0, hB1);

            w20.q = *(const u32x4*)(wp + (4 * 64 + l) * 4);
            w21.q = *(const u32x4*)(wp + (5 * 64 + l) * 4);
            a2A = __builtin_amdgcn_mfma_f32_32x32x16_bf16(w20.v, hA0, a2A, 0, 0, 0);
            a2B = __builtin_amdgcn_mfma_f32_32x32x16_bf16(w20.v, hB0, a2B, 0, 0, 0);
            a2A = __builtin_amdgcn_mfma_f32_32x32x16_bf16(w21.v, hA1, a2A, 0, 0, 0);
            a2B = __builtin_amdgcn_mfma_f32_32x32x16_bf16(w21.v, hB1, a2B, 0, 0, 0);

            bf16x8 gA0, gA1, gB0, gB1;
            reluT(a2A, gA0, gA1);
            reluT(a2B, gB0, gB1);

            w30.q = *(const u32x4*)(wp + (6 * 64 + l) * 4);
            w31.q = *(const u32x4*)(wp + (7 * 64 + l) * 4);
            f32x16 a3A = *(const f32x16*)(cl + ((s * 3 + 2) * 2 + hi) * 16);
            f32x16 a3B = a3A;
            a3A = __builtin_amdgcn_mfma_f32_32x32x16_bf16(w30.v, gA0, a3A, 0, 0, 0);
            a3B = __builtin_amdgcn_mfma_f32_32x32x16_bf16(w30.v, gB0, a3B, 0, 0, 0);
            a3A = __builtin_amdgcn_mfma_f32_32x32x16_bf16(w31.v, gA1, a3A, 0, 0, 0);
            a3B = __builtin_amdgcn_mfma_f32_32x32x16_bf16(w31.v, gB1, a3B, 0, 0, 0);

            // exec-masked stores: each row written exactly once (its species)
            if (svA == s && rowA < B) store_row(out + (long)rowA * 32 + hi * 4, a3A);
            if (svB == s && rowB < B) store_row(out + (long)rowB * 32 + hi * 4, a3B);
        }
    }
}

extern "C" void kernel_launch(void* const* d_in, const int* in_sizes, int n_in,
                              void* d_out, int out_size, void* d_ws, size_t ws_size,
                              hipStream_t stream) {
    const float* X   = (const float*)d_in[0];
    const int*   sid = (const int*)d_in[1];
    const float* W1  = (const float*)d_in[2];
    const float* b1  = (const float*)d_in[3];
    const float* g1  = (const float*)d_in[4];
    const float* be1 = (const float*)d_in[5];
    const float* mu1 = (const float*)d_in[6];
    const float* va1 = (const float*)d_in[7];
    const float* W2  = (const float*)d_in[8];
    const float* b2  = (const float*)d_in[9];
    const float* g2  = (const float*)d_in[10];
    const float* be2 = (const float*)d_in[11];
    const float* mu2 = (const float*)d_in[12];
    const float* va2 = (const float*)d_in[13];
    const float* Wsc = (const float*)d_in[14];
    const float* bsc = (const float*)d_in[15];
    const float* Wsh = (const float*)d_in[16];
    const float* bsh = (const float*)d_in[17];
    float* out = (float*)d_out;
    const int B = in_sizes[1];

    unsigned* wfrag = (unsigned*)d_ws;          // 10240 u32
    float* bconst   = (float*)(wfrag + 10240);  // 480 f32

    k_pre<<<41, 256, 0, stream>>>(wfrag, bconst,
                                  W1, b1, g1, be1, mu1, va1,
                                  W2, b2, g2, be2, mu2, va2,
                                  Wsc, bsc, Wsh, bsh);

    const int npairs = (B + 63) / 64;
    const int nblocks = min(MAXBLK, (npairs + 3) / 4);
    k_main<<<nblocks, TPB, 0, stream>>>(X, sid, wfrag, bconst, out, B, npairs);
}

// Round 8
// 79.517 us; speedup vs baseline: 1.5780x; 1.3668x over previous
//
#include <hip/hip_runtime.h>

// ---------------------------------------------------------------------------
// SpeciesSpecificNetworkBranch — windowed block-local compaction + bf16 MFMA.
//
// R4-R6 lesson: dense all-5-species redundancy has ~36us of inherent VALU
// issue-work (on top of a ~41us memory floor) and stays latency-bound.
// R3 lesson: GLOBAL species sorting turns X/out into device-wide random
// gather/scatter -> ~2TB/s effective HBM.
// R7: compact WITHIN a 1024-row window per block. Per-species index lists are
// built in LDS via ballot ranking (no global traffic), segments padded to 32.
// The block's 4 waves then run ~34 single-species tiles per window (vs 160
// redundant chains): 4.6x less compute. Gathers/scatters are random only
// inside a 128KB window, so HBM still sees unit-stride line coverage.
// R7 bug (fixed in R8): per-species const stride is 96 floats ([3][2][16]),
// phase B used 48 -> species 1..4 read wrong biases.
//
// Weights/biases are BN-folded (+0.92 branch weight) and frag-packed by k_pre,
// staged once to LDS (42KB, conflict-free reads, species is wave-uniform).
//
// math: z1 = W1^T x + b1
//       z2 = W2f^T relu(z1) + Wsc^T x + bias2f     (W2f = diag(A1) W2)
//       out = relu(Wshf_s^T relu(z2) + bshf_s)     (0.92 pre-folded)
// C'[feature][sample] via mfma_f32_32x32x16_bf16; sample lane-local, so
// relu + v_cvt_pk_bf16_f32 + permlane32_swap chains layers in registers.
// ---------------------------------------------------------------------------

#define EPSBN 1e-5f
#define TPB 256
#define NBLKMAX 768       // 3 blocks/CU
#define WROWS 1024        // rows per window
#define MAXSLOT 1184      // WROWS + 5*31 pad, rounded up
#define MAXTILE 37        // 32 + 5

typedef __attribute__((ext_vector_type(8))) short bf16x8;
typedef __attribute__((ext_vector_type(16))) float f32x16;
typedef __attribute__((ext_vector_type(4))) unsigned u32x4;

union FU { unsigned u[4]; bf16x8 v; u32x4 q; };

static __device__ __forceinline__ unsigned pkbf(float lo, float hi) {
    unsigned r;
    asm("v_cvt_pk_bf16_f32 %0, %1, %2" : "=v"(r) : "v"(lo), "v"(hi));
    return r;
}

// --- pre-pack: fold BN (and 0.92) into weights/biases, pack MFMA A-frags ---
// wfrag uints [s][m][c][64][4]  (m: 0=W1 1=Wsc 2=W2f 3=Wshf), 10240 words
// bconst floats [s][q][hi][16]  (q: 0=b1 1=bias2f 2=bshf), 480 floats
__global__ void k_pre(unsigned* __restrict__ wfrag, float* __restrict__ bconst,
                      const float* __restrict__ W1, const float* __restrict__ b1,
                      const float* __restrict__ g1, const float* __restrict__ be1,
                      const float* __restrict__ mu1, const float* __restrict__ va1,
                      const float* __restrict__ W2, const float* __restrict__ b2,
                      const float* __restrict__ g2, const float* __restrict__ be2,
                      const float* __restrict__ mu2, const float* __restrict__ va2,
                      const float* __restrict__ Wsc, const float* __restrict__ bsc,
                      const float* __restrict__ Wsh, const float* __restrict__ bsh) {
    if (blockIdx.x < 40) {
        const int i = blockIdx.x * 256 + threadIdx.x;   // wfrag word index
        const int p = i & 3, l = (i >> 2) & 63, c = (i >> 8) & 1;
        const int m = (i >> 9) & 3, s = i >> 11;
        const int ln = l & 31, hi = l >> 5;
        const int k0 = c * 16 + hi * 8 + 2 * p;
        float lo, hv;
        if (m == 0)      { lo = W1[s*1024 + k0*32 + ln];  hv = W1[s*1024 + (k0+1)*32 + ln]; }
        else if (m == 1) { lo = Wsc[s*1024 + k0*32 + ln]; hv = Wsc[s*1024 + (k0+1)*32 + ln]; }
        else if (m == 2) {
            float A0 = g1[s*32+k0]   * rsqrtf(va1[s*32+k0]   + EPSBN);
            float A1 = g1[s*32+k0+1] * rsqrtf(va1[s*32+k0+1] + EPSBN);
            lo = A0 * W2[s*1024 + k0*32 + ln]; hv = A1 * W2[s*1024 + (k0+1)*32 + ln];
        } else {
            float A0 = 0.92f * g2[s*32+k0]   * rsqrtf(va2[s*32+k0]   + EPSBN);
            float A1 = 0.92f * g2[s*32+k0+1] * rsqrtf(va2[s*32+k0+1] + EPSBN);
            lo = A0 * Wsh[k0*32 + ln]; hv = A1 * Wsh[(k0+1)*32 + ln];
        }
        wfrag[i] = pkbf(lo, hv);
    } else {
        for (int i = threadIdx.x; i < 480; i += 256) {
            const int reg = i & 15, hi = (i >> 4) & 1, t = i >> 5;
            const int q = t % 3, s = t / 3;
            const int r = (reg & 3) + 8 * (reg >> 2) + 4 * hi;
            float v;
            if (q == 0) v = b1[s*32 + r];
            else if (q == 1) {
                v = b2[s*32 + r] + bsc[s*32 + r];
                for (int k = 0; k < 32; ++k) {
                    float A = g1[s*32+k] * rsqrtf(va1[s*32+k] + EPSBN);
                    float C = be1[s*32+k] - mu1[s*32+k] * A;
                    v = fmaf(C, W2[s*1024 + k*32 + r], v);
                }
            } else {
                v = bsh[r];
                for (int k = 0; k < 32; ++k) {
                    float A = g2[s*32+k] * rsqrtf(va2[s*32+k] + EPSBN);
                    float C = be2[s*32+k] - mu2[s*32+k] * A;
                    v = fmaf(C, Wsh[k*32 + r], v);
                }
                v *= 0.92f;
            }
            bconst[i] = v;
        }
    }
}

// relu-only transition: C' acc -> next layer's B-frags (cvt_pk + permlane32).
static __device__ __forceinline__ void reluT(const f32x16& c, bf16x8& f0, bf16x8& f1) {
    unsigned p[8];
    #pragma unroll
    for (int i = 0; i < 8; ++i)
        p[i] = pkbf(fmaxf(c[2 * i], 0.f), fmaxf(c[2 * i + 1], 0.f));
    auto s0 = __builtin_amdgcn_permlane32_swap(p[0], p[2], false, false);
    auto s1 = __builtin_amdgcn_permlane32_swap(p[1], p[3], false, false);
    auto s2 = __builtin_amdgcn_permlane32_swap(p[4], p[6], false, false);
    auto s3 = __builtin_amdgcn_permlane32_swap(p[5], p[7], false, false);
    FU u0, u1;
    u0.u[0] = s0[0]; u0.u[1] = s1[0]; u0.u[2] = s0[1]; u0.u[3] = s1[1];
    u1.u[0] = s2[0]; u1.u[1] = s3[0]; u1.u[2] = s2[1]; u1.u[3] = s3[1];
    f0 = u0.v; f1 = u1.v;
}

struct XR { float4 a, b, c, d; };

static __device__ __forceinline__ XR ldx(const float* __restrict__ X, long ofs, int hi) {
    const float* xb = X + ofs + hi * 8;
    XR r;
    r.a = *(const float4*)(xb);
    r.b = *(const float4*)(xb + 4);
    r.c = *(const float4*)(xb + 16);
    r.d = *(const float4*)(xb + 20);
    return r;
}

static __device__ __forceinline__ void cvtx(const XR& x, bf16x8& b0, bf16x8& b1) {
    FU u0, u1;
    u0.u[0] = pkbf(x.a.x, x.a.y); u0.u[1] = pkbf(x.a.z, x.a.w);
    u0.u[2] = pkbf(x.b.x, x.b.y); u0.u[3] = pkbf(x.b.z, x.b.w);
    u1.u[0] = pkbf(x.c.x, x.c.y); u1.u[1] = pkbf(x.c.z, x.c.w);
    u1.u[2] = pkbf(x.d.x, x.d.y); u1.u[3] = pkbf(x.d.z, x.d.w);
    b0 = u0.v; b1 = u1.v;
}

static __device__ __forceinline__ void store_row(float* __restrict__ op, const f32x16& a3) {
    #pragma unroll
    for (int q = 0; q < 4; ++q) {
        float4 v;
        v.x = fmaxf(a3[4 * q + 0], 0.f);
        v.y = fmaxf(a3[4 * q + 1], 0.f);
        v.z = fmaxf(a3[4 * q + 2], 0.f);
        v.w = fmaxf(a3[4 * q + 3], 0.f);
        *(float4*)(op + q * 8) = v;
    }
}

__global__ __launch_bounds__(TPB, 3) void k_main(
    const float* __restrict__ X, const int* __restrict__ sid,
    const unsigned* __restrict__ wfrag, const float* __restrict__ bconst,
    float* __restrict__ out, int B) {
    __shared__ unsigned wlds[10240];
    __shared__ float clds[480];
    __shared__ int idxl[MAXSLOT];
    __shared__ int wq[4][4][5];
    __shared__ int tspec[MAXTILE];
    __shared__ int sgb[8];          // [0..4] segment slot base, [5] ntiles

    // stage weight/bias tables once per block
    for (int i = threadIdx.x; i < 10240; i += TPB) wlds[i] = wfrag[i];
    for (int i = threadIdx.x; i < 480; i += TPB) clds[i] = bconst[i];

    const int tid = threadIdx.x;
    const int l   = tid & 63;
    const int ln  = l & 31;
    const int hi  = l >> 5;
    const int wav = tid >> 6;
    const unsigned long long ltmask = (1ull << l) - 1ull;

    const int nwin = (B + WROWS - 1) / WROWS;

    for (int w = blockIdx.x; w < nwin; w += gridDim.x) {
        const int wbase = w * WROWS;

        // ---- pass 1: sentinel-fill idx array + per-(iter,wave) species counts
        for (int i = tid; i < MAXSLOT; i += TPB) idxl[i] = -1;
        int sv[4];
        #pragma unroll
        for (int it = 0; it < 4; ++it) {
            const int row = wbase + it * TPB + tid;
            sv[it] = (row < B) ? sid[row] : -1;
            #pragma unroll
            for (int sp = 0; sp < 5; ++sp) {
                unsigned long long m = __ballot(sv[it] == sp);
                if (l == 0) wq[it][wav][sp] = (int)__popcll(m);
            }
        }
        __syncthreads();

        // ---- pass 2: serial scan (thread 0): segment bases, tile table
        if (tid == 0) {
            int o = 0, tt = 0;
            for (int s = 0; s < 5; ++s) {
                int c = 0;
                for (int it = 0; it < 4; ++it)
                    for (int w2 = 0; w2 < 4; ++w2) c += wq[it][w2][s];
                sgb[s] = o;
                int nt = (c + 31) >> 5;
                for (int k = 0; k < nt; ++k) tspec[tt++] = s;
                o += nt << 5;
            }
            sgb[5] = tt;
        }
        __syncthreads();

        // ---- pass 3: ballot-rank each row into its species segment
        #pragma unroll
        for (int it = 0; it < 4; ++it) {
            const int s = sv[it];
            int rank = 0;
            #pragma unroll
            for (int sp = 0; sp < 5; ++sp) {
                unsigned long long m = __ballot(s == sp);
                if (s == sp) rank = (int)__popcll(m & ltmask);
            }
            if (s >= 0) {
                int off = sgb[s];
                for (int t2 = 0; t2 < it; ++t2)
                    #pragma unroll
                    for (int w2 = 0; w2 < 4; ++w2) off += wq[t2][w2][s];
                for (int w2 = 0; w2 < wav; ++w2) off += wq[it][w2][s];
                idxl[off + rank] = wbase + it * TPB + tid;
            }
        }
        __syncthreads();

        // ---- phase B: waves process single-species tiles, gather->chain->scatter
        const int ntl = sgb[5];
        int t = wav;
        int sp = 0, id = -1;
        XR xc;
        if (t < ntl) {
            sp = __builtin_amdgcn_readfirstlane(tspec[t]);
            id = idxl[t * 32 + ln];
            xc = ldx(X, (long)(id < 0 ? 0 : id) * 32, hi);
        }
        for (; t < ntl; t += 4) {
            bf16x8 b0, b1;
            cvtx(xc, b0, b1);
            const int csp = sp, cid = id;

            const int tn = t + 4;
            if (tn < ntl) {   // prefetch next tile
                sp = __builtin_amdgcn_readfirstlane(tspec[tn]);
                id = idxl[tn * 32 + ln];
                xc = ldx(X, (long)(id < 0 ? 0 : id) * 32, hi);
            }

            // single-species chain (csp wave-uniform -> scalar addressing)
            const unsigned* wp = wlds + csp * 2048;
            const float*    cp = clds + csp * 96;   // [3][2][16] per species (R7 bug: was 48)
            FU w00, w01, w10, w11, w20, w21, w30, w31;
            w00.q = *(const u32x4*)(wp + (0 * 64 + l) * 4);
            w01.q = *(const u32x4*)(wp + (1 * 64 + l) * 4);
            w10.q = *(const u32x4*)(wp + (2 * 64 + l) * 4);
            w11.q = *(const u32x4*)(wp + (3 * 64 + l) * 4);

            f32x16 a1 = *(const f32x16*)(cp + (0 * 2 + hi) * 16);
            f32x16 a2 = *(const f32x16*)(cp + (1 * 2 + hi) * 16);
            a1 = __builtin_amdgcn_mfma_f32_32x32x16_bf16(w00.v, b0, a1, 0, 0, 0);
            a2 = __builtin_amdgcn_mfma_f32_32x32x16_bf16(w10.v, b0, a2, 0, 0, 0);
            a1 = __builtin_amdgcn_mfma_f32_32x32x16_bf16(w01.v, b1, a1, 0, 0, 0);
            a2 = __builtin_amdgcn_mfma_f32_32x32x16_bf16(w11.v, b1, a2, 0, 0, 0);

            bf16x8 h0, h1;
            reluT(a1, h0, h1);
            w20.q = *(const u32x4*)(wp + (4 * 64 + l) * 4);
            w21.q = *(const u32x4*)(wp + (5 * 64 + l) * 4);
            a2 = __builtin_amdgcn_mfma_f32_32x32x16_bf16(w20.v, h0, a2, 0, 0, 0);
            a2 = __builtin_amdgcn_mfma_f32_32x32x16_bf16(w21.v, h1, a2, 0, 0, 0);

            bf16x8 g0, g1;
            reluT(a2, g0, g1);
            w30.q = *(const u32x4*)(wp + (6 * 64 + l) * 4);
            w31.q = *(const u32x4*)(wp + (7 * 64 + l) * 4);
            f32x16 a3 = *(const f32x16*)(cp + (2 * 2 + hi) * 16);
            a3 = __builtin_amdgcn_mfma_f32_32x32x16_bf16(w30.v, g0, a3, 0, 0, 0);
            a3 = __builtin_amdgcn_mfma_f32_32x32x16_bf16(w31.v, g1, a3, 0, 0, 0);

            if (cid >= 0) store_row(out + (long)cid * 32 + hi * 4, a3);
        }
        __syncthreads();   // protect idxl/tspec before next window overwrites
    }
}

extern "C" void kernel_launch(void* const* d_in, const int* in_sizes, int n_in,
                              void* d_out, int out_size, void* d_ws, size_t ws_size,
                              hipStream_t stream) {
    const float* X   = (const float*)d_in[0];
    const int*   sid = (const int*)d_in[1];
    const float* W1  = (const float*)d_in[2];
    const float* b1  = (const float*)d_in[3];
    const float* g1  = (const float*)d_in[4];
    const float* be1 = (const float*)d_in[5];
    const float* mu1 = (const float*)d_in[6];
    const float* va1 = (const float*)d_in[7];
    const float* W2  = (const float*)d_in[8];
    const float* b2  = (const float*)d_in[9];
    const float* g2  = (const float*)d_in[10];
    const float* be2 = (const float*)d_in[11];
    const float* mu2 = (const float*)d_in[12];
    const float* va2 = (const float*)d_in[13];
    const float* Wsc = (const float*)d_in[14];
    const float* bsc = (const float*)d_in[15];
    const float* Wsh = (const float*)d_in[16];
    const float* bsh = (const float*)d_in[17];
    float* out = (float*)d_out;
    const int B = in_sizes[1];

    unsigned* wfrag = (unsigned*)d_ws;          // 10240 u32
    float* bconst   = (float*)(wfrag + 10240);  // 480 f32

    k_pre<<<41, 256, 0, stream>>>(wfrag, bconst,
                                  W1, b1, g1, be1, mu1, va1,
                                  W2, b2, g2, be2, mu2, va2,
                                  Wsc, bsc, Wsh, bsh);

    const int nwin = (B + WROWS - 1) / WROWS;
    const int nblocks = min(NBLKMAX, nwin);
    k_main<<<nblocks, TPB, 0, stream>>>(X, sid, wfrag, bconst, out, B);
}

// Round 9
// 71.411 us; speedup vs baseline: 1.7571x; 1.1135x over previous
//
#include <hip/hip_runtime.h>

// ---------------------------------------------------------------------------
// SpeciesSpecificNetworkBranch — window-in-LDS compaction + bf16 MFMA.
//
// R8 post-mortem: per-lane scattered X-gathers (16B pieces, 64 cache lines per
// vector instr) are TA/L2-request bound -> ~2 TB/s with all pipes idle.
// R9: 256-row window per block. X staged COALESCEDLY into a 16KB bf16 LDS
// tile (XOR-swizzled); ballot-compaction (as R8, single-iter now); phase B
// reads B-frags from LDS (2x ds_read_b128, <=4-way conflicts) -> the
// scattered-read amplification disappears. Weights read from global per tile
// (coalesced, L1/L2-hot 42KB table) so LDS is ~20KB -> 4 blocks/CU.
// Out-stores remain direct scattered (fire-and-forget, within 32KB window).
//
// math: z1 = W1^T x + b1
//       z2 = W2f^T relu(z1) + Wsc^T x + bias2f     (W2f = diag(A1) W2)
//       out = relu(Wshf_s^T relu(z2) + bshf_s)     (0.92 pre-folded)
// C'[feature][sample] via mfma_f32_32x32x16_bf16; sample lane-local, so
// relu + v_cvt_pk_bf16_f32 + permlane32_swap chains layers in registers.
// ---------------------------------------------------------------------------

#define EPSBN 1e-5f
#define TPB 256
#define NBLKMAX 1024      // 4 blocks/CU
#define WIN 256           // rows per window (= TPB)

typedef __attribute__((ext_vector_type(8))) short bf16x8;
typedef __attribute__((ext_vector_type(16))) float f32x16;
typedef __attribute__((ext_vector_type(4))) unsigned u32x4;

union FU { unsigned u[4]; bf16x8 v; u32x4 q; };

static __device__ __forceinline__ unsigned pkbf(float lo, float hi) {
    unsigned r;
    asm("v_cvt_pk_bf16_f32 %0, %1, %2" : "=v"(r) : "v"(lo), "v"(hi));
    return r;
}

// --- pre-pack: fold BN (and 0.92) into weights/biases, pack MFMA A-frags ---
// wfrag uints [s][m][c][64][4]  (m: 0=W1 1=Wsc 2=W2f 3=Wshf), 10240 words
// bconst floats [s][q][hi][16]  (q: 0=b1 1=bias2f 2=bshf), 480 floats
__global__ void k_pre(unsigned* __restrict__ wfrag, float* __restrict__ bconst,
                      const float* __restrict__ W1, const float* __restrict__ b1,
                      const float* __restrict__ g1, const float* __restrict__ be1,
                      const float* __restrict__ mu1, const float* __restrict__ va1,
                      const float* __restrict__ W2, const float* __restrict__ b2,
                      const float* __restrict__ g2, const float* __restrict__ be2,
                      const float* __restrict__ mu2, const float* __restrict__ va2,
                      const float* __restrict__ Wsc, const float* __restrict__ bsc,
                      const float* __restrict__ Wsh, const float* __restrict__ bsh) {
    if (blockIdx.x < 40) {
        const int i = blockIdx.x * 256 + threadIdx.x;   // wfrag word index
        const int p = i & 3, l = (i >> 2) & 63, c = (i >> 8) & 1;
        const int m = (i >> 9) & 3, s = i >> 11;
        const int ln = l & 31, hi = l >> 5;
        const int k0 = c * 16 + hi * 8 + 2 * p;
        float lo, hv;
        if (m == 0)      { lo = W1[s*1024 + k0*32 + ln];  hv = W1[s*1024 + (k0+1)*32 + ln]; }
        else if (m == 1) { lo = Wsc[s*1024 + k0*32 + ln]; hv = Wsc[s*1024 + (k0+1)*32 + ln]; }
        else if (m == 2) {
            float A0 = g1[s*32+k0]   * rsqrtf(va1[s*32+k0]   + EPSBN);
            float A1 = g1[s*32+k0+1] * rsqrtf(va1[s*32+k0+1] + EPSBN);
            lo = A0 * W2[s*1024 + k0*32 + ln]; hv = A1 * W2[s*1024 + (k0+1)*32 + ln];
        } else {
            float A0 = 0.92f * g2[s*32+k0]   * rsqrtf(va2[s*32+k0]   + EPSBN);
            float A1 = 0.92f * g2[s*32+k0+1] * rsqrtf(va2[s*32+k0+1] + EPSBN);
            lo = A0 * Wsh[k0*32 + ln]; hv = A1 * Wsh[(k0+1)*32 + ln];
        }
        wfrag[i] = pkbf(lo, hv);
    } else {
        for (int i = threadIdx.x; i < 480; i += 256) {
            const int reg = i & 15, hi = (i >> 4) & 1, t = i >> 5;
            const int q = t % 3, s = t / 3;
            const int r = (reg & 3) + 8 * (reg >> 2) + 4 * hi;
            float v;
            if (q == 0) v = b1[s*32 + r];
            else if (q == 1) {
                v = b2[s*32 + r] + bsc[s*32 + r];
                for (int k = 0; k < 32; ++k) {
                    float A = g1[s*32+k] * rsqrtf(va1[s*32+k] + EPSBN);
                    float C = be1[s*32+k] - mu1[s*32+k] * A;
                    v = fmaf(C, W2[s*1024 + k*32 + r], v);
                }
            } else {
                v = bsh[r];
                for (int k = 0; k < 32; ++k) {
                    float A = g2[s*32+k] * rsqrtf(va2[s*32+k] + EPSBN);
                    float C = be2[s*32+k] - mu2[s*32+k] * A;
                    v = fmaf(C, Wsh[k*32 + r], v);
                }
                v *= 0.92f;
            }
            bconst[i] = v;
        }
    }
}

// relu-only transition: C' acc -> next layer's B-frags (cvt_pk + permlane32).
static __device__ __forceinline__ void reluT(const f32x16& c, bf16x8& f0, bf16x8& f1) {
    unsigned p[8];
    #pragma unroll
    for (int i = 0; i < 8; ++i)
        p[i] = pkbf(fmaxf(c[2 * i], 0.f), fmaxf(c[2 * i + 1], 0.f));
    auto s0 = __builtin_amdgcn_permlane32_swap(p[0], p[2], false, false);
    auto s1 = __builtin_amdgcn_permlane32_swap(p[1], p[3], false, false);
    auto s2 = __builtin_amdgcn_permlane32_swap(p[4], p[6], false, false);
    auto s3 = __builtin_amdgcn_permlane32_swap(p[5], p[7], false, false);
    FU u0, u1;
    u0.u[0] = s0[0]; u0.u[1] = s1[0]; u0.u[2] = s0[1]; u0.u[3] = s1[1];
    u1.u[0] = s2[0]; u1.u[1] = s3[0]; u1.u[2] = s2[1]; u1.u[3] = s3[1];
    f0 = u0.v; f1 = u1.v;
}

static __device__ __forceinline__ void store_row(float* __restrict__ op, const f32x16& a3) {
    #pragma unroll
    for (int q = 0; q < 4; ++q) {
        float4 v;
        v.x = fmaxf(a3[4 * q + 0], 0.f);
        v.y = fmaxf(a3[4 * q + 1], 0.f);
        v.z = fmaxf(a3[4 * q + 2], 0.f);
        v.w = fmaxf(a3[4 * q + 3], 0.f);
        *(float4*)(op + q * 8) = v;
    }
}

__global__ __launch_bounds__(TPB, 4) void k_main(
    const float* __restrict__ X, const int* __restrict__ sid,
    const unsigned* __restrict__ wfrag, const float* __restrict__ bconst,
    float* __restrict__ out, int B) {
    // LDS: bf16 window tile [256 rows][4 slots x 16B], XOR-swizzled slots
    __shared__ __align__(16) unsigned char xb[16384];
    __shared__ float clds[480];
    __shared__ int idxl[416];       // 256 + 5*31 padded slots
    __shared__ int wq[4][5];
    __shared__ int tspec[16];
    __shared__ int sgb[8];

    const int tid = threadIdx.x;
    const int l   = tid & 63;
    const int ln  = l & 31;
    const int hi  = l >> 5;
    const int wav = tid >> 6;
    const unsigned long long ltmask = (1ull << l) - 1ull;

    for (int i = tid; i < 480; i += TPB) clds[i] = bconst[i];

    const int nwin = (B + WIN - 1) / WIN;
    for (int w = blockIdx.x; w < nwin; w += gridDim.x) {
        __syncthreads();   // prev window's phase-B readers done before restage
        const int wbase = w * WIN;

        // ---- stage X coalesced -> bf16 LDS (swizzled). 4 iters x 8 floats/t.
        const long fmax = (long)B * 32 - 8;
        #pragma unroll
        for (int k = 0; k < 4; ++k) {
            long fo = (long)wbase * 32 + k * 2048 + tid * 8;
            if (fo > fmax) fo = fmax;
            float4 xa = *(const float4*)(X + fo);
            float4 xc = *(const float4*)(X + fo + 4);
            FU u;
            u.u[0] = pkbf(xa.x, xa.y); u.u[1] = pkbf(xa.z, xa.w);
            u.u[2] = pkbf(xc.x, xc.y); u.u[3] = pkbf(xc.z, xc.w);
            const int row  = k * 64 + (tid >> 2);
            const int slot = (tid & 3) ^ (row & 3);
            *(u32x4*)(xb + row * 64 + slot * 16) = u.q;
        }

        // ---- species, per-wave counts, in-wave rank; sentinel-fill idxl
        const int myrow = wbase + tid;
        const int s = (myrow < B) ? sid[myrow] : -1;
        int prank = 0;
        #pragma unroll
        for (int sp = 0; sp < 5; ++sp) {
            unsigned long long m = __ballot(s == sp);
            if (l == 0) wq[wav][sp] = (int)__popcll(m);
            if (s == sp) prank = (int)__popcll(m & ltmask);
        }
        for (int i = tid; i < 416; i += TPB) idxl[i] = -1;
        __syncthreads();

        // ---- serial scan: segment bases + tile->species table
        if (tid == 0) {
            int o = 0, tt = 0;
            for (int sp = 0; sp < 5; ++sp) {
                int c = wq[0][sp] + wq[1][sp] + wq[2][sp] + wq[3][sp];
                sgb[sp] = o;
                int nt = (c + 31) >> 5;
                for (int kk = 0; kk < nt; ++kk) tspec[tt++] = sp;
                o += nt << 5;
            }
            sgb[5] = tt;
        }
        __syncthreads();

        // ---- rank-write local row index into species segment
        if (s >= 0) {
            int off = sgb[s] + prank;
            for (int w2 = 0; w2 < wav; ++w2) off += wq[w2][s];
            idxl[off] = tid;
        }
        __syncthreads();

        // ---- phase B: single-species tiles; frags from LDS, weights global
        const int ntl = sgb[5];
        for (int t = wav; t < ntl; t += 4) {
            const int csp = __builtin_amdgcn_readfirstlane(tspec[t]);
            const int lid = idxl[t * 32 + ln];
            const int r = lid < 0 ? 0 : lid;

            const unsigned* wp = wfrag + csp * 2048;   // coalesced, L1/L2-hot
            FU w00, w01, w10, w11, w20, w21, w30, w31;
            w00.q = *(const u32x4*)(wp + (0 * 64 + l) * 4);
            w01.q = *(const u32x4*)(wp + (1 * 64 + l) * 4);
            w10.q = *(const u32x4*)(wp + (2 * 64 + l) * 4);
            w11.q = *(const u32x4*)(wp + (3 * 64 + l) * 4);
            w20.q = *(const u32x4*)(wp + (4 * 64 + l) * 4);
            w21.q = *(const u32x4*)(wp + (5 * 64 + l) * 4);
            w30.q = *(const u32x4*)(wp + (6 * 64 + l) * 4);
            w31.q = *(const u32x4*)(wp + (7 * 64 + l) * 4);

            const float* cp = clds + csp * 96;
            f32x16 a1 = *(const f32x16*)(cp + hi * 16);
            f32x16 a2 = *(const f32x16*)(cp + 32 + hi * 16);

            const int rs = r & 3;
            const bf16x8 b0 = *(const bf16x8*)(xb + r * 64 + ((hi ^ rs) << 4));
            const bf16x8 b1 = *(const bf16x8*)(xb + r * 64 + (((2 + hi) ^ rs) << 4));

            a1 = __builtin_amdgcn_mfma_f32_32x32x16_bf16(w00.v, b0, a1, 0, 0, 0);
            a2 = __builtin_amdgcn_mfma_f32_32x32x16_bf16(w10.v, b0, a2, 0, 0, 0);
            a1 = __builtin_amdgcn_mfma_f32_32x32x16_bf16(w01.v, b1, a1, 0, 0, 0);
            a2 = __builtin_amdgcn_mfma_f32_32x32x16_bf16(w11.v, b1, a2, 0, 0, 0);

            bf16x8 h0, h1;
            reluT(a1, h0, h1);
            a2 = __builtin_amdgcn_mfma_f32_32x32x16_bf16(w20.v, h0, a2, 0, 0, 0);
            a2 = __builtin_amdgcn_mfma_f32_32x32x16_bf16(w21.v, h1, a2, 0, 0, 0);

            bf16x8 g0, g1;
            reluT(a2, g0, g1);
            f32x16 a3 = *(const f32x16*)(cp + 64 + hi * 16);
            a3 = __builtin_amdgcn_mfma_f32_32x32x16_bf16(w30.v, g0, a3, 0, 0, 0);
            a3 = __builtin_amdgcn_mfma_f32_32x32x16_bf16(w31.v, g1, a3, 0, 0, 0);

            if (lid >= 0) store_row(out + (long)(wbase + lid) * 32 + hi * 4, a3);
        }
    }
}

extern "C" void kernel_launch(void* const* d_in, const int* in_sizes, int n_in,
                              void* d_out, int out_size, void* d_ws, size_t ws_size,
                              hipStream_t stream) {
    const float* X   = (const float*)d_in[0];
    const int*   sid = (const int*)d_in[1];
    const float* W1  = (const float*)d_in[2];
    const float* b1  = (const float*)d_in[3];
    const float* g1  = (const float*)d_in[4];
    const float* be1 = (const float*)d_in[5];
    const float* mu1 = (const float*)d_in[6];
    const float* va1 = (const float*)d_in[7];
    const float* W2  = (const float*)d_in[8];
    const float* b2  = (const float*)d_in[9];
    const float* g2  = (const float*)d_in[10];
    const float* be2 = (const float*)d_in[11];
    const float* mu2 = (const float*)d_in[12];
    const float* va2 = (const float*)d_in[13];
    const float* Wsc = (const float*)d_in[14];
    const float* bsc = (const float*)d_in[15];
    const float* Wsh = (const float*)d_in[16];
    const float* bsh = (const float*)d_in[17];
    float* out = (float*)d_out;
    const int B = in_sizes[1];

    unsigned* wfrag = (unsigned*)d_ws;          // 10240 u32
    float* bconst   = (float*)(wfrag + 10240);  // 480 f32

    k_pre<<<41, 256, 0, stream>>>(wfrag, bconst,
                                  W1, b1, g1, be1, mu1, va1,
                                  W2, b2, g2, be2, mu2, va2,
                                  Wsc, bsc, Wsh, bsh);

    const int nwin = (B + WIN - 1) / WIN;
    const int nblocks = min(NBLKMAX, nwin);
    k_main<<<nblocks, TPB, 0, stream>>>(X, sid, wfrag, bconst, out, B);
}